// Round 9
// baseline (691.874 us; speedup 1.0000x reference)
//
#include <hip/hip_runtime.h>

#define NN 100000
#define EC 6400000
#define ED 400000
#define BN_EPS 1e-5f
#define NSB ((NN + 255) >> 8)    // 391 buckets of 256 nodes
#define NCH 256                  // edge chunks == scatter/hist grid
#define CSR_CAP 19200            // LDS CSR build capacity (padded mean 17152 + slack)
#define CHUNK_OF(E) (((((E) + NCH - 1) / NCH) + 3) & ~3)   // 4-aligned chunk

// ---------------- preprocessing (R5-proven; + 4-aligned per-node CSR pads) ----

__global__ __launch_bounds__(1024)
void hist_pass(const int* __restrict__ ei, int E, int* __restrict__ bhist) {
    __shared__ int h[NSB];
    for (int i = threadIdx.x; i < NSB; i += 1024) h[i] = 0;
    __syncthreads();
    int k = blockIdx.x;
    int chunk = CHUNK_OF(E);
    int beg = k * chunk, end = min(E, beg + chunk);
    for (int e = beg + threadIdx.x * 4; e < end; e += 1024 * 4) {
        int4 d4 = *(const int4*)&ei[E + e];
        atomicAdd(&h[d4.x >> 8], 1);
        atomicAdd(&h[d4.y >> 8], 1);
        atomicAdd(&h[d4.z >> 8], 1);
        atomicAdd(&h[d4.w >> 8], 1);
    }
    __syncthreads();
    for (int i = threadIdx.x; i < NSB; i += 1024) bhist[i * NCH + k] = h[i];
}

__global__ __launch_bounds__(256)
void row_scan(int* __restrict__ bhist, int* __restrict__ total) {
    int b = blockIdx.x;
    int* row = bhist + b * NCH;
    __shared__ int wsum[4];
    int lane = threadIdx.x & 63, w = threadIdx.x >> 6;
    int v = row[threadIdx.x];
    int x = v;
    #pragma unroll
    for (int sh = 1; sh < 64; sh <<= 1) { int y = __shfl_up(x, sh); if (lane >= sh) x += y; }
    if (lane == 63) wsum[w] = x;
    __syncthreads();
    int wb = 0;
    #pragma unroll
    for (int j = 0; j < 4; ++j) if (j < w) wb += wsum[j];
    row[threadIdx.x] = wb + x - v;
    if (threadIdx.x == 255) total[b] = wb + x;
}

// bbase: packed-array bases (real counts). cbase: csr bases (padded upper
// bound: per-bucket ceil4 + 1024 slack for per-node ceil4 padding), 4-aligned.
__global__ void bucket_base(const int* __restrict__ total,
                            int* __restrict__ bbase, int* __restrict__ cbase) {
    __shared__ int wsum[4], wsum2[4];
    __shared__ int carry, carry2;
    if (threadIdx.x == 0) { carry = 0; carry2 = 0; }
    __syncthreads();
    int lane = threadIdx.x & 63, w = threadIdx.x >> 6;
    for (int s = 0; s < NSB; s += 256) {
        int idx = s + threadIdx.x;
        int v  = (idx < NSB) ? total[idx] : 0;
        int v2 = (idx < NSB) ? (((total[idx] + 3) & ~3) + 1024) : 0;
        int x = v, x2 = v2;
        #pragma unroll
        for (int sh = 1; sh < 64; sh <<= 1) {
            int y = __shfl_up(x, sh);  if (lane >= sh) x += y;
            int y2 = __shfl_up(x2, sh); if (lane >= sh) x2 += y2;
        }
        if (lane == 63) { wsum[w] = x; wsum2[w] = x2; }
        __syncthreads();
        int wb = 0, wb2 = 0;
        #pragma unroll
        for (int j = 0; j < 4; ++j) if (j < w) { wb += wsum[j]; wb2 += wsum2[j]; }
        int all = wsum[0] + wsum[1] + wsum[2] + wsum[3];
        int all2 = wsum2[0] + wsum2[1] + wsum2[2] + wsum2[3];
        if (idx < NSB) { bbase[idx] = carry + wb + x - v; cbase[idx] = carry2 + wb2 + x2 - v2; }
        __syncthreads();
        if (threadIdx.x == 0) { carry += all; carry2 += all2; }
        __syncthreads();
    }
}

__global__ __launch_bounds__(1024)
void scatter_pairs(const int* __restrict__ ei, int E,
                   const int* __restrict__ bhist, const int* __restrict__ bbase,
                   unsigned* __restrict__ packed) {
    __shared__ int cur[NSB];
    int k = blockIdx.x;
    for (int b = threadIdx.x; b < NSB; b += 1024)
        cur[b] = bbase[b] + bhist[b * NCH + k];
    __syncthreads();
    int chunk = CHUNK_OF(E);
    int beg = k * chunk, end = min(E, beg + chunk);
    for (int e = beg + threadIdx.x * 4; e < end; e += 1024 * 4) {
        int4 s4 = *(const int4*)&ei[e];
        int4 d4 = *(const int4*)&ei[E + e];
        { int p = atomicAdd(&cur[d4.x >> 8], 1); packed[p] = (unsigned)s4.x | ((unsigned)(d4.x & 255) << 17); }
        { int p = atomicAdd(&cur[d4.y >> 8], 1); packed[p] = (unsigned)s4.y | ((unsigned)(d4.y & 255) << 17); }
        { int p = atomicAdd(&cur[d4.z >> 8], 1); packed[p] = (unsigned)s4.z | ((unsigned)(d4.z & 255) << 17); }
        { int p = atomicAdd(&cur[d4.w >> 8], 1); packed[p] = (unsigned)s4.w | ((unsigned)(d4.w & 255) << 17); }
    }
}

// per-node segments padded to x4 (int4 csr loads in the layer kernel)
__global__ __launch_bounds__(256)
void sb_csr(const unsigned* __restrict__ packed,
            const int* __restrict__ bbase, const int* __restrict__ total,
            const int* __restrict__ cbase,
            int* __restrict__ csr, int* __restrict__ offs, int* __restrict__ deg,
            float* __restrict__ inv) {
    __shared__ int h[256];
    __shared__ int loff[256];
    __shared__ int ws2[4];
    __shared__ int ptot_s;
    __shared__ int ebuf[CSR_CAP];
    int b = blockIdx.x;
    int ebeg = bbase[b], ecnt = total[b], cbeg = cbase[b];
    int node0 = b << 8;
    int nn = min(256, NN - node0);
    h[threadIdx.x] = 0;
    __syncthreads();
    for (int e = threadIdx.x; e < ecnt; e += 256)
        atomicAdd(&h[packed[ebeg + e] >> 17], 1);
    __syncthreads();
    {
        int lane = threadIdx.x & 63, w = threadIdx.x >> 6;
        int v = h[threadIdx.x];
        int pv = (v + 3) & ~3;                    // padded slot size
        int x = pv;
        #pragma unroll
        for (int sh = 1; sh < 64; sh <<= 1) { int y = __shfl_up(x, sh); if (lane >= sh) x += y; }
        if (lane == 63) ws2[w] = x;
        __syncthreads();
        int wb = 0;
        #pragma unroll
        for (int j = 0; j < 4; ++j) if (j < w) wb += ws2[j];
        int excl = wb + x - pv;
        loff[threadIdx.x] = excl;
        if (threadIdx.x == 255) ptot_s = wb + x;
        if (threadIdx.x < nn) {
            int node = node0 + threadIdx.x;
            offs[node] = cbeg + excl;
            deg[node]  = v;
            inv[node]  = 1.0f / (float)(v > 1 ? v : 1);
        }
    }
    __syncthreads();
    int ptot = ptot_s;
    if (ptot <= CSR_CAP) {
        for (int e = threadIdx.x; e < ecnt; e += 256) {
            unsigned u = packed[ebeg + e];
            int p = atomicAdd(&loff[u >> 17], 1);
            ebuf[p] = (int)(u & 0x1FFFF);
        }
        __syncthreads();
        for (int e = threadIdx.x; e < ptot; e += 256) csr[cbeg + e] = ebuf[e];
    } else {   // overflow fallback (never fires for this data)
        for (int e = threadIdx.x; e < ecnt; e += 256) {
            unsigned u = packed[ebeg + e];
            int p = atomicAdd(&loff[u >> 17], 1);
            csr[cbeg + p] = (int)(u & 0x1FFFF);
        }
    }
}

// prep: x (f32 [NN,5]) -> f32 padded [NN,8]; W1 (8x5) -> padded 8x8
__global__ __launch_bounds__(256)
void prep_misc(const float* __restrict__ x, const float* __restrict__ W1l,
               const float* __restrict__ W1r, float* __restrict__ xp,
               float* __restrict__ W1lp, float* __restrict__ W1rp) {
    int t = blockIdx.x * 256 + threadIdx.x;
    if (t < 64) {
        int f = t >> 3, k = t & 7;
        W1lp[t] = (k < 5) ? W1l[f * 5 + k] : 0.f;
        W1rp[t] = (k < 5) ? W1r[f * 5 + k] : 0.f;
    }
    for (int idx = t; idx < NN * 8; idx += gridDim.x * 256) {
        int f = idx & 7, i = idx >> 3;
        xp[idx] = (f < 5) ? x[i * 5 + f] : 0.f;
    }
}

// ---------------- fused SAGE layer v4: 4x-unrolled gather (MLP) ----------------
// R8 was latency-bound: ~2 outstanding gathers/wave x 18 waves = 36 lines
// in flight per CU -> 0.09 lines/cyc (Little's law matched 88us). Now each
// lane loads 4 csr entries (int4; per-node segments 4-aligned/padded) and
// issues 8 independent dwordx4 row loads before consuming -> ~4x MLP.
// Exact grid (3125 blocks = 100K nodes), no grid-stride, no bounds checks.
template<bool APPLY_BN>
__global__ __launch_bounds__(256)
void sage_layer8(const float* __restrict__ hin,
                 const float* __restrict__ stats_in,   // padded: [k*16]=sum, [(8+k)*16]=sumsq
                 const float* __restrict__ gin, const float* __restrict__ bin,
                 const int* __restrict__ offs, const int* __restrict__ deg,
                 const int* __restrict__ csr, const float* __restrict__ inv,
                 const float* __restrict__ Wl, const float* __restrict__ Wr,
                 float* __restrict__ hout, float* __restrict__ stats_out) {
    __shared__ float bl[16];
    int tid = threadIdx.x;
    if (tid < 16) bl[tid] = 0.f;
    __syncthreads();
    int wave = tid >> 6, lane = tid & 63, g = lane >> 3, f = lane & 7;

    float sc[8], sh[8];
    #pragma unroll
    for (int k = 0; k < 8; ++k) { sc[k] = 1.f; sh[k] = 0.f; }
    if constexpr (APPLY_BN) {
        #pragma unroll
        for (int k = 0; k < 8; ++k) {
            float m = stats_in[k * 16] * (1.f / NN);
            float v = stats_in[(8 + k) * 16] * (1.f / NN) - m * m;
            float is = rsqrtf(v + BN_EPS);
            sc[k] = gin[k] * is;
            sh[k] = bin[k] - m * sc[k];
        }
    }
    float wl[8], wr[8];
    #pragma unroll
    for (int k = 0; k < 8; ++k) { wl[k] = Wl[f * 8 + k]; wr[k] = Wr[f * 8 + k]; }

    int i = (blockIdx.x * 4 + wave) * 8 + g;      // exact cover: i < NN always
    int d = deg[i];
    int o = offs[i];
    const int e0 = f * 4;
    float a0 = 0, a1 = 0, a2 = 0, a3 = 0, a4 = 0, a5 = 0, a6 = 0, a7 = 0;
    for (int b = 0; b < d; b += 32) {             // 32 edges/node/iter, 4 per lane
        int base = b + e0;
        int4 c4 = *(const int4*)(csr + o + base); // o 4-aligned by construction
        unsigned s0 = min((unsigned)c4.x & 0x1FFFFu, (unsigned)(NN - 1));
        unsigned s1 = min((unsigned)c4.y & 0x1FFFFu, (unsigned)(NN - 1));
        unsigned s2 = min((unsigned)c4.z & 0x1FFFFu, (unsigned)(NN - 1));
        unsigned s3 = min((unsigned)c4.w & 0x1FFFFu, (unsigned)(NN - 1));
        const float4* p0 = (const float4*)(hin + (size_t)s0 * 8);
        const float4* p1 = (const float4*)(hin + (size_t)s1 * 8);
        const float4* p2 = (const float4*)(hin + (size_t)s2 * 8);
        const float4* p3 = (const float4*)(hin + (size_t)s3 * 8);
        float4 r00 = p0[0], r01 = p0[1];          // 8 independent 16B loads in flight
        float4 r10 = p1[0], r11 = p1[1];
        float4 r20 = p2[0], r21 = p2[1];
        float4 r30 = p3[0], r31 = p3[1];
        float m0 = (base + 0 < d) ? 1.f : 0.f;
        float m1 = (base + 1 < d) ? 1.f : 0.f;
        float m2 = (base + 2 < d) ? 1.f : 0.f;
        float m3 = (base + 3 < d) ? 1.f : 0.f;
        a0 = fmaf(r00.x, m0, a0); a1 = fmaf(r00.y, m0, a1);
        a2 = fmaf(r00.z, m0, a2); a3 = fmaf(r00.w, m0, a3);
        a4 = fmaf(r01.x, m0, a4); a5 = fmaf(r01.y, m0, a5);
        a6 = fmaf(r01.z, m0, a6); a7 = fmaf(r01.w, m0, a7);
        a0 = fmaf(r10.x, m1, a0); a1 = fmaf(r10.y, m1, a1);
        a2 = fmaf(r10.z, m1, a2); a3 = fmaf(r10.w, m1, a3);
        a4 = fmaf(r11.x, m1, a4); a5 = fmaf(r11.y, m1, a5);
        a6 = fmaf(r11.z, m1, a6); a7 = fmaf(r11.w, m1, a7);
        a0 = fmaf(r20.x, m2, a0); a1 = fmaf(r20.y, m2, a1);
        a2 = fmaf(r20.z, m2, a2); a3 = fmaf(r20.w, m2, a3);
        a4 = fmaf(r21.x, m2, a4); a5 = fmaf(r21.y, m2, a5);
        a6 = fmaf(r21.z, m2, a6); a7 = fmaf(r21.w, m2, a7);
        a0 = fmaf(r30.x, m3, a0); a1 = fmaf(r30.y, m3, a1);
        a2 = fmaf(r30.z, m3, a2); a3 = fmaf(r30.w, m3, a3);
        a4 = fmaf(r31.x, m3, a4); a5 = fmaf(r31.y, m3, a5);
        a6 = fmaf(r31.z, m3, a6); a7 = fmaf(r31.w, m3, a7);
    }
    #pragma unroll
    for (int msk = 1; msk < 8; msk <<= 1) {       // group-wide sums, all lanes
        a0 += __shfl_xor(a0, msk); a1 += __shfl_xor(a1, msk);
        a2 += __shfl_xor(a2, msk); a3 += __shfl_xor(a3, msk);
        a4 += __shfl_xor(a4, msk); a5 += __shfl_xor(a5, msk);
        a6 += __shfl_xor(a6, msk); a7 += __shfl_xor(a7, msk);
    }
    float im = inv[i];
    float dnz = (d > 0) ? 1.f : 0.f;              // BN shift only if node has neighbors
    const float4* hp = (const float4*)(hin + (size_t)i * 8);
    float4 h0 = hp[0];
    float4 h1 = hp[1];
    float hk[8] = { h0.x, h0.y, h0.z, h0.w, h1.x, h1.y, h1.z, h1.w };
    float ac[8] = { a0, a1, a2, a3, a4, a5, a6, a7 };
    float y = 0.f;
    #pragma unroll
    for (int k = 0; k < 8; ++k) {
        float mk = fmaf(sc[k], ac[k] * im, sh[k] * dnz);
        float hh = fmaf(sc[k], hk[k], sh[k]);
        y = fmaf(mk, wl[k], y);
        y = fmaf(hh, wr[k], y);
    }
    float n2 = y * y;
    n2 += __shfl_xor(n2, 1);
    n2 += __shfl_xor(n2, 2);
    n2 += __shfl_xor(n2, 4);
    float z = y / fmaxf(sqrtf(n2), 1e-12f);
    float r = fmaxf(z, 0.f);
    hout[(size_t)i * 8 + f] = r;                  // 64 consecutive floats: coalesced
    atomicAdd(&bl[f], r);
    atomicAdd(&bl[8 + f], r * r);
    __syncthreads();
    if (tid < 16) atomicAdd(&stats_out[tid * 16], bl[tid]);   // 1 cache line per feature
}

__global__ void apply_bn_out(const float* __restrict__ hin,
                             const float* __restrict__ stats,
                             const float* __restrict__ g, const float* __restrict__ b,
                             float* __restrict__ out) {
    int t = blockIdx.x * blockDim.x + threadIdx.x;
    if (t >= NN * 8) return;
    int f = t & 7;
    float m = stats[f * 16] * (1.0f / NN);
    float v = stats[(8 + f) * 16] * (1.0f / NN) - m * m;
    float sc = g[f] * rsqrtf(v + BN_EPS);
    float sh = b[f] - m * sc;
    out[t] = fmaf(hin[t], sc, sh);
}

// ---------------- launch ----------------

static inline char* bump(char*& p, size_t bytes) {
    char* r = p;
    p += (bytes + 255) & ~(size_t)255;
    return r;
}

extern "C" void kernel_launch(void* const* d_in, const int* in_sizes, int n_in,
                              void* d_out, int out_size, void* d_ws, size_t ws_size,
                              hipStream_t stream) {
    const float* x   = (const float*)d_in[0];
    const int* eic   = (const int*)d_in[1];
    const int* eid   = (const int*)d_in[2];
    const float* W1l = (const float*)d_in[3];
    const float* W1r = (const float*)d_in[4];
    const float* W2l = (const float*)d_in[5];
    const float* W2r = (const float*)d_in[6];
    const float* W3l = (const float*)d_in[7];
    const float* W3r = (const float*)d_in[8];
    const float* W4l = (const float*)d_in[9];
    const float* W4r = (const float*)d_in[10];
    const float* g1 = (const float*)d_in[11];
    const float* b1 = (const float*)d_in[12];
    const float* g2 = (const float*)d_in[13];
    const float* b2 = (const float*)d_in[14];
    const float* g3 = (const float*)d_in[15];
    const float* b3 = (const float*)d_in[16];
    const float* g4 = (const float*)d_in[17];
    const float* b4 = (const float*)d_in[18];
    float* out = (float*)d_out;

    const size_t CPAD = (size_t)NSB * 1024 + 2048;   // per-bucket csr padding slack

    char* p = (char*)d_ws;
    float* stats   = (float*)bump(p, 5 * 256 * 4);   // zero region (only this)
    size_t zero_bytes = (size_t)(p - (char*)d_ws);
    int*   bhist_c = (int*)  bump(p, (size_t)NSB * NCH * 4);
    int*   bhist_d = (int*)  bump(p, (size_t)NSB * NCH * 4);
    int*   total_c = (int*)  bump(p, NSB * 4);
    int*   bbase_c = (int*)  bump(p, NSB * 4);
    int*   cbase_c = (int*)  bump(p, NSB * 4);
    int*   total_d = (int*)  bump(p, NSB * 4);
    int*   bbase_d = (int*)  bump(p, NSB * 4);
    int*   cbase_d = (int*)  bump(p, NSB * 4);
    int*   offs_c  = (int*)  bump(p, NN * 4);
    int*   deg_c   = (int*)  bump(p, NN * 4);
    float* inv_c   = (float*)bump(p, NN * 4);
    int*   offs_d  = (int*)  bump(p, NN * 4);
    int*   deg_d   = (int*)  bump(p, NN * 4);
    float* inv_d   = (float*)bump(p, NN * 4);
    int*   csr_c   = (int*)  bump(p, ((size_t)EC + CPAD) * 4);
    int*   csr_d   = (int*)  bump(p, ((size_t)ED + CPAD) * 4);
    float* xp32    = (float*)bump(p, (size_t)NN * 8 * 4);
    float* W1lp    = (float*)bump(p, 64 * 4);
    float* W1rp    = (float*)bump(p, 64 * 4);
    unsigned* packed_d = (unsigned*)bump(p, (size_t)ED * 4);
    // packed_c dead after sb_csr; overlay f32 activation ping-pong buffers
    char* pc = p;
    unsigned* packed_c = (unsigned*)bump(p, (size_t)EC * 4);
    char* pr = pc;
    float* r_a = (float*)bump(pr, (size_t)NN * 8 * 4);
    float* r_b = (float*)bump(pr, (size_t)NN * 8 * 4);
    (void)ws_size; (void)in_sizes; (void)n_in; (void)out_size;

    hipMemsetAsync(d_ws, 0, zero_bytes, stream);

    hist_pass<<<NCH, 1024, 0, stream>>>(eic, EC, bhist_c);
    hist_pass<<<NCH, 1024, 0, stream>>>(eid, ED, bhist_d);
    row_scan<<<NSB, 256, 0, stream>>>(bhist_c, total_c);
    row_scan<<<NSB, 256, 0, stream>>>(bhist_d, total_d);
    bucket_base<<<1, 256, 0, stream>>>(total_c, bbase_c, cbase_c);
    bucket_base<<<1, 256, 0, stream>>>(total_d, bbase_d, cbase_d);
    scatter_pairs<<<NCH, 1024, 0, stream>>>(eic, EC, bhist_c, bbase_c, packed_c);
    scatter_pairs<<<NCH, 1024, 0, stream>>>(eid, ED, bhist_d, bbase_d, packed_d);
    sb_csr<<<NSB, 256, 0, stream>>>(packed_c, bbase_c, total_c, cbase_c, csr_c, offs_c, deg_c, inv_c);
    sb_csr<<<NSB, 256, 0, stream>>>(packed_d, bbase_d, total_d, cbase_d, csr_d, offs_d, deg_d, inv_d);
    prep_misc<<<512, 256, 0, stream>>>(x, W1l, W1r, xp32, W1lp, W1rp);

    const int LB = (NN + 31) / 32;   // 3125 blocks x 4 waves x 8 nodes = exactly NN
    sage_layer8<false><<<LB, 256, 0, stream>>>(
        xp32, nullptr, nullptr, nullptr,
        offs_c, deg_c, csr_c, inv_c, W1lp, W1rp, r_a, stats + 0);
    sage_layer8<true><<<LB, 256, 0, stream>>>(
        r_a, stats + 0, g1, b1,
        offs_c, deg_c, csr_c, inv_c, W4l, W4r, r_b, stats + 256);
    sage_layer8<true><<<LB, 256, 0, stream>>>(
        r_b, stats + 256, g2, b2,
        offs_d, deg_d, csr_d, inv_d, W2l, W2r, r_a, stats + 512);
    sage_layer8<true><<<LB, 256, 0, stream>>>(
        r_a, stats + 512, g3, b3,
        offs_c, deg_c, csr_c, inv_c, W3l, W3r, r_b, stats + 768);
    sage_layer8<true><<<LB, 256, 0, stream>>>(
        r_b, stats + 768, g4, b4,
        offs_c, deg_c, csr_c, inv_c, W3l, W3r, r_a, stats + 1024);
    apply_bn_out<<<(NN * 8 + 255) / 256, 256, 0, stream>>>(r_a, stats + 1024, g4, b4, out);
}